// Round 6
// baseline (456.747 us; speedup 1.0000x reference)
//
#include <hip/hip_runtime.h>
#include <hip/hip_bf16.h>

typedef __hip_bfloat16 bf16;
typedef __attribute__((ext_vector_type(8))) short short8;   // 8 bf16 = 4 VGPRs
typedef __attribute__((ext_vector_type(4))) float float4v;  // MFMA C/D
typedef __attribute__((ext_vector_type(4))) short short4v;

__device__ __forceinline__ short f2bs(float x) {
    bf16 b = __float2bfloat16(x);
    return *reinterpret_cast<short*>(&b);
}
__device__ __forceinline__ float bs2f(short s) {
    bf16 b = *reinterpret_cast<bf16*>(&s);
    return __bfloat162float(b);
}

#define GLL16(g, l) __builtin_amdgcn_global_load_lds(                      \
    (const __attribute__((address_space(1))) void*)(g),                    \
    (__attribute__((address_space(3))) void*)(l), 16, 0, 0)

// ---------------- preprocessing: f32 -> padded bf16 layouts ----------------

// emb (50000,300) f32 -> emb_bf (50176,320) bf16, zero pad rows & cols.
__global__ __launch_bounds__(256) void conv_emb(
    const float* __restrict__ src, short* __restrict__ dst)
{
    const int idx = blockIdx.x * 256 + threadIdx.x;      // 50176*80
    if (idx >= 50176 * 80) return;
    const int row = idx / 80;
    const int k4  = (idx - row * 80) * 4;
    short4v v;
#pragma unroll
    for (int j = 0; j < 4; ++j)
        v[j] = (row < 50000 && k4 + j < 300)
                   ? f2bs(src[(long)row * 300 + k4 + j]) : (short)0;
    *(short4v*)&dst[(long)row * 320 + k4] = v;
}

// W_leaf (300,300) -> Bleaf (320,320) bf16 zero-padded
__global__ __launch_bounds__(256) void conv_wleaf(
    const float* __restrict__ src, short* __restrict__ dst)
{
    const int idx = blockIdx.x * 256 + threadIdx.x;      // 320*320
    if (idx >= 320 * 320) return;
    const int row = idx / 320, k = idx - row * 320;
    dst[idx] = (row < 300 && k < 300) ? f2bs(src[row * 300 + k]) : (short)0;
}

// W_h (300,600) -> Bh (320,640): k'<300 -> k'; 320<=k'<620 -> k'-20; else 0
__global__ __launch_bounds__(256) void conv_wh(
    const float* __restrict__ src, short* __restrict__ dst)
{
    const int idx = blockIdx.x * 256 + threadIdx.x;      // 320*640
    if (idx >= 320 * 640) return;
    const int row = idx / 640, k = idx - row * 640;
    float v = 0.f;
    if (row < 300) {
        if (k < 300)                 v = src[row * 600 + k];
        else if (k >= 320 && k < 620) v = src[row * 600 + k - 20];
    }
    dst[idx] = f2bs(v);
}

// b_h (300,) -> biasp (320,) f32 zero-padded
__global__ __launch_bounds__(320) void conv_bias(
    const float* __restrict__ src, float* __restrict__ dst)
{
    const int i = threadIdx.x;
    if (i < 320) dst[i] = (i < 300) ? src[i] : 0.f;
}

// ---------------- MFMA GEMM (3-buffer, 2-deep prefetch, role-split) --------
// out(M,320 bf16) = X(M,KE bf16) @ Wp(320,KE bf16)^T (+ biasp), KE in {320,640}.
// GMODE 0: A rows read directly from Xsrc.
// GMODE 2 (KE=640): A-row m = concat(Hv[wid[2m]], Hv[wid[2m+1]]) gathered.
// Block: 512 thr = 8 waves (4x2); tile M=256 x N=320. Wave tile 64x160 =
// 4 M x 10 N frags of v_mfma_f32_16x16x32_bf16 (same regs as the 4-wave ver:
// reg-bound at ~2 waves/SIMD, so one 8-wave block/CU == old 2 blocks/CU).
// Staging role-split: waves 0-3 stage B (5 groups, vmcnt(10)), waves 4-7
// stage A (4 groups, vmcnt(8)). Loads issued 2 chunks ahead into 3 LDS
// buffers; counted vmcnt never drains to 0 mid-loop -> gather latency
// (L2-miss -> L3, ~500-900cy) hides under 2 chunks of compute.
template <int KE, int GMODE, bool BIAS>
__global__ __launch_bounds__(512, 2) void mfma_gemm(
    const short* __restrict__ Xsrc, const int* __restrict__ wid,
    const short* __restrict__ emb, const short* __restrict__ Wp,
    const float* __restrict__ biasp, short* __restrict__ out)
{
    static_assert(GMODE != 2 || KE == 640, "pair-gather requires KE=640");
    __shared__ __align__(16) short As[3][256 * 32];   // 3 x 16 KB
    __shared__ __align__(16) short Bs[3][320 * 32];   // 3 x 20 KB -> 108 KB

    const int tid  = threadIdx.x;
    const int lane = tid & 63;
    const int w    = tid >> 6;            // 0..7
    const int wm   = w >> 1, wn = w & 1;  // 4x2 wave grid
    const long m0  = (long)blockIdx.x * 256;

    const int s_q   = lane & 3;     // this lane's LDS k-quarter slot
    const int r_off = lane >> 2;    // row within 16-row staging group
    const bool isB  = (w < 4);      // waves 0-3 stage B, waves 4-7 stage A

    // staging global pointers (chunk-invariant bases) + LDS group offsets
    const char* gP[5];
    const char* gR[4];
    int         lo[5];
    if (isB) {
#pragma unroll
        for (int j = 0; j < 5; ++j) {
            const int g = w * 5 + j;                  // 0..19
            const int r = g * 16 + r_off;             // 0..319
            const int q = s_q ^ ((r >> 1) & 3);       // global k-quarter
            gP[j] = (const char*)Wp + r * (long)(KE * 2) + q * 16;
            lo[j] = g * 1024;
        }
    } else {
#pragma unroll
        for (int j = 0; j < 4; ++j) {
            const int g = (w - 4) * 4 + j;            // 0..15
            const int r = g * 16 + r_off;             // 0..255
            const int q = s_q ^ ((r >> 1) & 3);
            if (GMODE == 2) {
                const long node = m0 + r;
                gP[j] = (const char*)emb + (long)wid[2 * node]     * 640 + q * 16;
                gR[j] = (const char*)emb + (long)wid[2 * node + 1] * 640 + q * 16;
            } else {
                gP[j] = (const char*)Xsrc + (m0 + r) * (long)(KE * 2) + q * 16;
                gR[j] = gP[j];
            }
            lo[j] = g * 1024;
        }
    }

    // stage chunk kc into buffer buf (wave-uniform LDS dest, lane*16 scatter)
    auto stage = [&](int buf, int kc) {
        if (isB) {
            char* base = (char*)&Bs[buf][0];
            const long off = (long)kc * 64;
#pragma unroll
            for (int j = 0; j < 5; ++j) GLL16(gP[j] + off, base + lo[j]);
        } else {
            char* base = (char*)&As[buf][0];
            if (GMODE == 2) {
                // chunks 0..9 = left gathered row, 10..19 = right gathered row
                const bool lft = (kc < 10);
                const long off = (long)(lft ? kc : kc - 10) * 64;
#pragma unroll
                for (int j = 0; j < 4; ++j)
                    GLL16((lft ? gP[j] : gR[j]) + off, base + lo[j]);
            } else {
                const long off = (long)kc * 64;
#pragma unroll
                for (int j = 0; j < 4; ++j) GLL16(gP[j] + off, base + lo[j]);
            }
        }
    };

    // fragment LDS offsets (element units, buffer-invariant)
    int oA[4];
#pragma unroll
    for (int t = 0; t < 4; ++t) {
        const int row = wm * 64 + t * 16 + (lane & 15);   // 0..255
        const int s   = (lane >> 4) ^ ((row >> 1) & 3);
        oA[t] = row * 32 + s * 8;
    }
    int oB[10];
#pragma unroll
    for (int u = 0; u < 10; ++u) {
        const int n = wn * 160 + u * 16 + (lane & 15);    // 0..319
        const int s = (lane >> 4) ^ ((n >> 1) & 3);
        oB[u] = n * 32 + s * 8;
    }

    float4v acc[4][10];
#pragma unroll
    for (int t = 0; t < 4; ++t)
#pragma unroll
        for (int u = 0; u < 10; ++u) acc[t][u] = (float4v)0.f;

    const int NCH = KE / 32;            // 10 or 20 (>= 3 always)
    stage(0, 0);
    stage(1, 1);
    int cur = 0;
    for (int kc = 0; kc < NCH; ++kc) {
        int nb = cur + 2; if (nb >= 3) nb -= 3;
        if (kc + 2 < NCH) {
            stage(nb, kc + 2);          // 2-deep: chunks kc+1, kc+2 in flight
            // wait until <= 2 chunks outstanding => chunk kc fully landed
            if (isB) asm volatile("s_waitcnt vmcnt(10)" ::: "memory");
            else     asm volatile("s_waitcnt vmcnt(8)"  ::: "memory");
        } else if (kc + 1 < NCH) {
            if (isB) asm volatile("s_waitcnt vmcnt(5)" ::: "memory");
            else     asm volatile("s_waitcnt vmcnt(4)" ::: "memory");
        } else {
            asm volatile("s_waitcnt vmcnt(0)" ::: "memory");
        }
        __builtin_amdgcn_s_barrier();   // all waves' chunk-kc stores landed
        __builtin_amdgcn_sched_barrier(0);

        const short* bA = &As[cur][0];
        const short* bB = &Bs[cur][0];
        short8 a[4], b[10];
#pragma unroll
        for (int t = 0; t < 4; ++t) a[t] = *(const short8*)(bA + oA[t]);
#pragma unroll
        for (int u = 0; u < 10; ++u) b[u] = *(const short8*)(bB + oB[u]);
#pragma unroll
        for (int u = 0; u < 10; ++u)
#pragma unroll
            for (int t = 0; t < 4; ++t)
                acc[t][u] = __builtin_amdgcn_mfma_f32_16x16x32_bf16(
                    a[t], b[u], acc[t][u], 0, 0, 0);
        __builtin_amdgcn_s_barrier();   // reads of buf[cur] done; iter kc+1's
                                        // stage may overwrite it ((kc+3)%3==cur-1)
        cur = (cur + 1 == 3) ? 0 : cur + 1;
    }

    // epilogue: C/D layout col=lane&15, row=(lane>>4)*4+reg
#pragma unroll
    for (int u = 0; u < 10; ++u) {
        const int c = wn * 160 + u * 16 + (lane & 15);
        const float bv = BIAS ? biasp[c] : 0.f;
#pragma unroll
        for (int t = 0; t < 4; ++t) {
            const long mb = m0 + wm * 64 + t * 16 + (lane >> 4) * 4;
#pragma unroll
            for (int r4 = 0; r4 < 4; ++r4)
                out[(mb + r4) * 320 + c] = f2bs(acc[t][u][r4] + bv);
        }
    }
}

// ---------------- classifier ----------------
// roots: 512 rows of 640 bf16 (pads at 300..320, 620..640). One wave per row.
__global__ __launch_bounds__(64) void cls_kernel(
    const short* __restrict__ roots, const float* __restrict__ W_cls,
    const float* __restrict__ b_cls, float* __restrict__ out)
{
    const int b    = blockIdx.x;
    const int lane = threadIdx.x;
    const short* row = roots + (long)b * 640;

    float a0 = 0.f, a1 = 0.f, a2 = 0.f;
#pragma unroll
    for (int i = 0; i < 10; ++i) {
        const int k = lane + 64 * i;
        if (k < 600) {
            const int col = (k < 300) ? k : k + 20;
            const float f = 1.f / (1.f + __expf(-bs2f(row[col])));
            a0 += f * W_cls[k];
            a1 += f * W_cls[600 + k];
            a2 += f * W_cls[1200 + k];
        }
    }
#pragma unroll
    for (int off = 32; off > 0; off >>= 1) {
        a0 += __shfl_down(a0, off);
        a1 += __shfl_down(a1, off);
        a2 += __shfl_down(a2, off);
    }
    if (lane == 0) {
        const float l0 = a0 + b_cls[0];
        const float l1 = a1 + b_cls[1];
        const float l2 = a2 + b_cls[2];
        const float m  = fmaxf(l0, fmaxf(l1, l2));
        const float s  = __expf(l0 - m) + __expf(l1 - m) + __expf(l2 - m);
        const float ls = m + __logf(s);
        out[b * 3 + 0] = l0 - ls;
        out[b * 3 + 1] = l1 - ls;
        out[b * 3 + 2] = l2 - ls;
    }
}

extern "C" void kernel_launch(void* const* d_in, const int* in_sizes, int n_in,
                              void* d_out, int out_size, void* d_ws, size_t ws_size,
                              hipStream_t stream)
{
    const int*   wid    = (const int*)d_in[0];     // (512,2,256) int32
    const float* emb    = (const float*)d_in[1];   // (50000,300) f32
    const float* W_leaf = (const float*)d_in[2];   // (300,300)
    const float* W_h    = (const float*)d_in[3];   // (300,600)
    const float* b_h    = (const float*)d_in[4];   // (300,)
    const float* W_cls  = (const float*)d_in[5];   // (3,600)
    const float* b_cls  = (const float*)d_in[6];   // (3,)
    float* outp = (float*)d_out;                   // (512,3) f32

    (void)in_sizes; (void)n_in; (void)out_size; (void)ws_size;

    // ws layout (peak 158,557,440 B):
    //   bufA   @ 0           : 131072*320*2 =  83,886,080  (tree ping)
    //   bufB   @  83,886,080 :  65536*320*2 =  41,943,040  (tree pong)
    //   emb_bf @  83,886,080 : 50176*320*2  =  32,112,640  (ALIASES bufB: dead
    //            after Hv GEMM; bufB first written at L2, which runs later)
    //   Hv     @ 125,829,120 : 50176*320*2  =  32,112,640  (vocab leaf hidden)
    //   Bleaf  @ 157,941,760 : 320*320*2    =     204,800
    //   Bh     @ 158,146,560 : 320*640*2    =     409,600
    //   biasp  @ 158,556,160 : 320*4        =       1,280
    char* ws = (char*)d_ws;
    short* bufA   = (short*)(ws);
    short* bufB   = (short*)(ws + 83886080);
    short* emb_bf = (short*)(ws + 83886080);
    short* Hv     = (short*)(ws + 125829120);
    short* Bleaf  = (short*)(ws + 157941760);
    short* Bh     = (short*)(ws + 158146560);
    float* biasp  = (float*)(ws + 158556160);

    conv_emb  <<<(50176 * 80) / 256, 256, 0, stream>>>(emb, emb_bf);
    conv_wleaf<<<(320 * 320) / 256, 256, 0, stream>>>(W_leaf, Bleaf);
    conv_wh   <<<(320 * 640) / 256, 256, 0, stream>>>(W_h, Bh);
    conv_bias <<<1, 320, 0, stream>>>(b_h, biasp);

    // Vocab-level leaf transform: Hv = emb_bf @ Bleaf^T, M=50176 (196 blocks).
    // Rows 50000..50175 are zero (never gathered anyway).
    mfma_gemm<320, 0, false><<<50176 / 256, 512, 0, stream>>>(
        emb_bf, nullptr, nullptr, Bleaf, biasp, Hv);

    // L1: node m = W_h @ concat(Hv[wid[2m]], Hv[wid[2m+1]]) + b_h.
    mfma_gemm<640, 2, true><<<131072 / 256, 512, 0, stream>>>(
        nullptr, wid, Hv, Bh, biasp, bufA);

    // L2..L8: node m reads prev rows 2m,2m+1 = contiguous 640 bf16 (pads align
    // with Bh's zero k-columns). Ping-pong bufA <-> bufB.
    short* cur = bufA;
    short* nxt = bufB;
    int nodes = 65536;
    for (int l = 0; l < 7; ++l) {
        mfma_gemm<640, 0, true><<<nodes / 256, 512, 0, stream>>>(
            cur, nullptr, nullptr, Bh, biasp, nxt);
        short* t = cur; cur = nxt; nxt = t;
        nodes >>= 1;
    }
    // roots: cur holds 1024 rows x 320 -> 512 x 640 view

    cls_kernel<<<512, 64, 0, stream>>>(cur, W_cls, b_cls, outp);
}

// Round 9
// 360.958 us; speedup vs baseline: 1.2654x; 1.2654x over previous
//
#include <hip/hip_runtime.h>
#include <hip/hip_bf16.h>

typedef __hip_bfloat16 bf16;
typedef __attribute__((ext_vector_type(8))) short short8;   // 8 bf16 = 4 VGPRs
typedef __attribute__((ext_vector_type(4))) float float4v;  // MFMA C/D
typedef __attribute__((ext_vector_type(4))) short short4v;

__device__ __forceinline__ short f2bs(float x) {
    bf16 b = __float2bfloat16(x);
    return *reinterpret_cast<short*>(&b);
}
__device__ __forceinline__ float bs2f(short s) {
    bf16 b = *reinterpret_cast<bf16*>(&s);
    return __bfloat162float(b);
}

#define GLL16(g, l) __builtin_amdgcn_global_load_lds(                      \
    (const __attribute__((address_space(1))) void*)(g),                    \
    (__attribute__((address_space(3))) void*)(l), 16, 0, 0)

// ---------------- preprocessing: f32 -> padded bf16 layouts ----------------

// emb (50000,300) f32 -> emb_bf (50176,320) bf16. float4 loads (row stride
// 1200 B and k4*4 are both 16B-aligned; k4<300 => k4<=296 => all 4 in-bounds).
__global__ __launch_bounds__(256) void conv_emb(
    const float* __restrict__ src, short* __restrict__ dst)
{
    const int idx = blockIdx.x * 256 + threadIdx.x;      // 50176*80
    if (idx >= 50176 * 80) return;
    const int row = idx / 80;
    const int k4  = (idx - row * 80) * 4;
    short4v v = (short4v)0;
    if (row < 50000 && k4 < 300) {
        const float4v f = *reinterpret_cast<const float4v*>(
            src + (long)row * 300 + k4);
#pragma unroll
        for (int j = 0; j < 4; ++j) v[j] = f2bs(f[j]);
    }
    *(short4v*)&dst[(long)row * 320 + k4] = v;
}

// Fused weight prep: W_h -> Bh (320x640), W_leaf -> Bleaf (320x320),
// b_h -> biasp (320). One kernel, three index regions.
__global__ __launch_bounds__(256) void conv_w(
    const float* __restrict__ W_h, const float* __restrict__ W_leaf,
    const float* __restrict__ b_h, short* __restrict__ Bh,
    short* __restrict__ Bleaf, float* __restrict__ biasp)
{
    const int idx = blockIdx.x * 256 + threadIdx.x;
    if (idx < 204800) {                                   // Bh 320x640
        const int row = idx / 640, k = idx - row * 640;
        float v = 0.f;
        if (row < 300) {
            if (k < 300)                  v = W_h[row * 600 + k];
            else if (k >= 320 && k < 620) v = W_h[row * 600 + k - 20];
        }
        Bh[idx] = f2bs(v);
    } else if (idx < 307200) {                            // Bleaf 320x320
        const int i = idx - 204800;
        const int row = i / 320, k = i - row * 320;
        Bleaf[i] = (row < 300 && k < 300) ? f2bs(W_leaf[row * 300 + k])
                                          : (short)0;
    } else if (idx < 307520) {                            // biasp 320
        const int i = idx - 307200;
        biasp[i] = (i < 300) ? b_h[i] : 0.f;
    }
}

// ---------------- MFMA GEMM (round-4 core: 2-buf, 1-deep counted vmcnt) ----
// out(M,320 bf16) = X(M,KE bf16) @ Wp(320,KE bf16)^T (+ biasp), KE in {320,640}.
// GMODE 0: A rows read directly from Xsrc.
// GMODE 2 (KE=640): A-row m = concat(Hv[wid[2m]], Hv[wid[2m+1]]) gathered.
// Block: 256 thr = 4 waves 2x2; tile M=128 x N=320 (full N). Wave: 64x160.
template <int KE, int GMODE, bool BIAS>
__global__ __launch_bounds__(256, 2) void mfma_gemm(
    const short* __restrict__ Xsrc, const int* __restrict__ wid,
    const short* __restrict__ emb, const short* __restrict__ Wp,
    const float* __restrict__ biasp, short* __restrict__ out)
{
    static_assert(GMODE != 2 || KE == 640, "pair-gather requires KE=640");
    __shared__ __align__(16) short As[2][128 * 32];   // 2 x 8 KB
    __shared__ __align__(16) short Bs[2][320 * 32];   // 2 x 20 KB

    const int tid  = threadIdx.x;
    const int lane = tid & 63;
    const int w    = tid >> 6;
    const int wm   = w >> 1, wn = w & 1;
    const long m0  = (long)blockIdx.x * 128;

    const int s_q   = lane & 3;
    const int r_off = lane >> 2;

    const char* gL[2];
    const char* gR[2];
#pragma unroll
    for (int j = 0; j < 2; ++j) {
        const int r = (w * 2 + j) * 16 + r_off;            // 0..127
        const int q = s_q ^ ((r >> 1) & 3);
        if (GMODE == 2) {
            const long node = m0 + r;
            gL[j] = (const char*)emb + (long)wid[2 * node]     * 640 + q * 16;
            gR[j] = (const char*)emb + (long)wid[2 * node + 1] * 640 + q * 16;
        } else {
            gL[j] = (const char*)Xsrc + (m0 + r) * (long)(KE * 2) + q * 16;
            gR[j] = gL[j];
        }
    }
    const char* gB[5];
#pragma unroll
    for (int j = 0; j < 5; ++j) {
        const int r = (w * 5 + j) * 16 + r_off;            // 0..319
        const int q = s_q ^ ((r >> 1) & 3);
        gB[j] = (const char*)Wp + r * (long)(KE * 2) + q * 16;
    }

    int oA[4];
#pragma unroll
    for (int t = 0; t < 4; ++t) {
        const int row = wm * 64 + t * 16 + (lane & 15);
        const int s   = (lane >> 4) ^ ((row >> 1) & 3);
        oA[t] = row * 32 + s * 8;
    }
    int oB[10];
#pragma unroll
    for (int u = 0; u < 10; ++u) {
        const int n = wn * 160 + u * 16 + (lane & 15);
        const int s = (lane >> 4) ^ ((n >> 1) & 3);
        oB[u] = n * 32 + s * 8;
    }

    auto stage = [&](int buf, int kc) {
        char* baseA = (char*)&As[buf][0];
        char* baseB = (char*)&Bs[buf][0];
        if (GMODE == 2) {
            const bool lft = (kc < 10);
            const int off = (lft ? kc : kc - 10) * 64;
            GLL16((lft ? gL[0] : gR[0]) + off, baseA + (w * 2 + 0) * 1024);
            GLL16((lft ? gL[1] : gR[1]) + off, baseA + (w * 2 + 1) * 1024);
        } else {
            const int off = kc * 64;
            GLL16(gL[0] + off, baseA + (w * 2 + 0) * 1024);
            GLL16(gL[1] + off, baseA + (w * 2 + 1) * 1024);
        }
        const int offb = kc * 64;
#pragma unroll
        for (int j = 0; j < 5; ++j)
            GLL16(gB[j] + offb, baseB + (w * 5 + j) * 1024);
    };

    float4v acc[4][10];
#pragma unroll
    for (int t = 0; t < 4; ++t)
#pragma unroll
        for (int u = 0; u < 10; ++u) acc[t][u] = (float4v)0.f;

    const int NCH = KE / 32;
    stage(0, 0);
    for (int kc = 0; kc < NCH; ++kc) {
        const int cur = kc & 1;
        if (kc + 1 < NCH) {
            stage(cur ^ 1, kc + 1);
            asm volatile("s_waitcnt vmcnt(7)" ::: "memory");
        } else {
            asm volatile("s_waitcnt vmcnt(0)" ::: "memory");
        }
        __builtin_amdgcn_s_barrier();
        __builtin_amdgcn_sched_barrier(0);

        const short* bA = &As[cur][0];
        const short* bB = &Bs[cur][0];
        short8 a[4], b[10];
#pragma unroll
        for (int t = 0; t < 4; ++t) a[t] = *(const short8*)(bA + oA[t]);
#pragma unroll
        for (int u = 0; u < 10; ++u) b[u] = *(const short8*)(bB + oB[u]);
#pragma unroll
        for (int u = 0; u < 10; ++u)
#pragma unroll
            for (int t = 0; t < 4; ++t)
                acc[t][u] = __builtin_amdgcn_mfma_f32_16x16x32_bf16(
                    a[t], b[u], acc[t][u], 0, 0, 0);
        __builtin_amdgcn_s_barrier();
    }

#pragma unroll
    for (int u = 0; u < 10; ++u) {
        const int c = wn * 160 + u * 16 + (lane & 15);
        const float bv = BIAS ? biasp[c] : 0.f;
#pragma unroll
        for (int t = 0; t < 4; ++t) {
            const long mb = m0 + wm * 64 + t * 16 + (lane >> 4) * 4;
#pragma unroll
            for (int r4 = 0; r4 < 4; ++r4)
                out[(mb + r4) * 320 + c] = f2bs(acc[t][u][r4] + bv);
        }
    }
}

// ---------------- fused level-pair GEMM ----------------
// Stage 1: level l, BM=128 out rows/block, A from Xsrc (GMODE 0), bias.
//   Output is NOT written to HBM; it is ds_written into Ahold in the staged
//   chunk-plane layout (plane kc: [64 rows][4 kq slots, XOR-swizzled]) that
//   stage 2's fragment reads expect. k' = (r&1)*320 + c => plane (r&1)*10+(c>>5);
//   quarter (c>>3)&3, offset c&7, slot q^((m2>>1)&3).
// Stage 2: level l+1, M=64/block, A read from Ahold (zero staging), B via
//   GLL 2-buf counted vmcnt(5), bias, out -> global.
// LDS: As 16K + Bs 40K + Ahold 80K = 136 KB (1 block/CU; tail levels only).
__global__ __launch_bounds__(256, 1) void mfma_pair(
    const short* __restrict__ Xsrc, const short* __restrict__ Wp,
    const float* __restrict__ biasp, short* __restrict__ out2)
{
    __shared__ __align__(16) short As[2][128 * 32];
    __shared__ __align__(16) short Bs[2][320 * 32];
    __shared__ __align__(16) short Ahold[20 * 2048];  // 20 planes x 64r x 32sh

    const int tid  = threadIdx.x;
    const int lane = tid & 63;
    const int w    = tid >> 6;
    const int wm   = w >> 1, wn = w & 1;
    const long m0  = (long)blockIdx.x * 128;          // stage-1 out rows

    const int s_q   = lane & 3;
    const int r_off = lane >> 2;

    const char* gA[2];
#pragma unroll
    for (int j = 0; j < 2; ++j) {
        const int r = (w * 2 + j) * 16 + r_off;
        const int q = s_q ^ ((r >> 1) & 3);
        gA[j] = (const char*)Xsrc + (m0 + r) * (long)(640 * 2) + q * 16;
    }
    const char* gB[5];
#pragma unroll
    for (int j = 0; j < 5; ++j) {
        const int r = (w * 5 + j) * 16 + r_off;
        const int q = s_q ^ ((r >> 1) & 3);
        gB[j] = (const char*)Wp + r * (long)(640 * 2) + q * 16;
    }

    int oB[10];
#pragma unroll
    for (int u = 0; u < 10; ++u) {
        const int n = wn * 160 + u * 16 + (lane & 15);
        const int s = (lane >> 4) ^ ((n >> 1) & 3);
        oB[u] = n * 32 + s * 8;
    }

    // ---- stage 1 ----
    {
        int oA[4];
#pragma unroll
        for (int t = 0; t < 4; ++t) {
            const int row = wm * 64 + t * 16 + (lane & 15);
            const int s   = (lane >> 4) ^ ((row >> 1) & 3);
            oA[t] = row * 32 + s * 8;
        }
        auto stage = [&](int buf, int kc) {
            char* baseA = (char*)&As[buf][0];
            char* baseB = (char*)&Bs[buf][0];
            const int off = kc * 64;
            GLL16(gA[0] + off, baseA + (w * 2 + 0) * 1024);
            GLL16(gA[1] + off, baseA + (w * 2 + 1) * 1024);
#pragma unroll
            for (int j = 0; j < 5; ++j)
                GLL16(gB[j] + off, baseB + (w * 5 + j) * 1024);
        };

        float4v acc[4][10];
#pragma unroll
        for (int t = 0; t < 4; ++t)
#pragma unroll
            for (int u = 0; u < 10; ++u) acc[t][u] = (float4v)0.f;

        stage(0, 0);
        for (int kc = 0; kc < 20; ++kc) {
            const int cur = kc & 1;
            if (kc + 1 < 20) {
                stage(cur ^ 1, kc + 1);
                asm volatile("s_waitcnt vmcnt(7)" ::: "memory");
            } else {
                asm volatile("s_waitcnt vmcnt(0)" ::: "memory");
            }
            __builtin_amdgcn_s_barrier();
            __builtin_amdgcn_sched_barrier(0);

            const short* bA = &As[cur][0];
            const short* bB = &Bs[cur][0];
            short8 a[4], b[10];
#pragma unroll
            for (int t = 0; t < 4; ++t) a[t] = *(const short8*)(bA + oA[t]);
#pragma unroll
            for (int u = 0; u < 10; ++u) b[u] = *(const short8*)(bB + oB[u]);
#pragma unroll
            for (int u = 0; u < 10; ++u)
#pragma unroll
                for (int t = 0; t < 4; ++t)
                    acc[t][u] = __builtin_amdgcn_mfma_f32_16x16x32_bf16(
                        a[t], b[u], acc[t][u], 0, 0, 0);
            __builtin_amdgcn_s_barrier();
        }

        // epilogue-1: out value (r,c) -> Ahold staged layout (LDS only)
#pragma unroll
        for (int u = 0; u < 10; ++u) {
            const int c  = wn * 160 + u * 16 + (lane & 15);
            const float bv = biasp[c];
            const int kcl = c >> 5;            // 0..9
            const int qs0 = (c >> 3) & 3;
            const int o   = c & 7;
#pragma unroll
            for (int t = 0; t < 4; ++t) {
                const int rb = wm * 64 + t * 16 + (lane >> 4) * 4;
#pragma unroll
                for (int r4 = 0; r4 < 4; ++r4) {
                    const int r  = rb + r4;
                    const int m2 = r >> 1;
                    const int kc2 = (r & 1) * 10 + kcl;
                    const int qs  = qs0 ^ ((m2 >> 1) & 3);
                    Ahold[kc2 * 2048 + m2 * 32 + qs * 8 + o] =
                        f2bs(acc[t][u][r4] + bv);
                }
            }
        }
    }
    __syncthreads();   // Ahold complete; stage-1 Bs reads done

    // ---- stage 2: M=64, A from Ahold, B staged ----
    {
        int oA2[2];
#pragma unroll
        for (int t = 0; t < 2; ++t) {
            const int row = wm * 32 + t * 16 + (lane & 15);    // 0..63
            const int s   = (lane >> 4) ^ ((row >> 1) & 3);
            oA2[t] = row * 32 + s * 8;
        }
        auto stageB = [&](int buf, int kc) {
            char* baseB = (char*)&Bs[buf][0];
            const int off = kc * 64;
#pragma unroll
            for (int j = 0; j < 5; ++j)
                GLL16(gB[j] + off, baseB + (w * 5 + j) * 1024);
        };

        float4v acc2[2][10];
#pragma unroll
        for (int t = 0; t < 2; ++t)
#pragma unroll
            for (int u = 0; u < 10; ++u) acc2[t][u] = (float4v)0.f;

        stageB(0, 0);
        for (int kc = 0; kc < 20; ++kc) {
            const int cur = kc & 1;
            if (kc + 1 < 20) {
                stageB(cur ^ 1, kc + 1);
                asm volatile("s_waitcnt vmcnt(5)" ::: "memory");
            } else {
                asm volatile("s_waitcnt vmcnt(0)" ::: "memory");
            }
            __builtin_amdgcn_s_barrier();
            __builtin_amdgcn_sched_barrier(0);

            const short* bA = &Ahold[kc * 2048];
            const short* bB = &Bs[cur][0];
            short8 a[2], b[10];
#pragma unroll
            for (int t = 0; t < 2; ++t) a[t] = *(const short8*)(bA + oA2[t]);
#pragma unroll
            for (int u = 0; u < 10; ++u) b[u] = *(const short8*)(bB + oB[u]);
#pragma unroll
            for (int u = 0; u < 10; ++u)
#pragma unroll
                for (int t = 0; t < 2; ++t)
                    acc2[t][u] = __builtin_amdgcn_mfma_f32_16x16x32_bf16(
                        a[t], b[u], acc2[t][u], 0, 0, 0);
            __builtin_amdgcn_s_barrier();
        }

        const long mo2 = (long)blockIdx.x * 64;
#pragma unroll
        for (int u = 0; u < 10; ++u) {
            const int c  = wn * 160 + u * 16 + (lane & 15);
            const float bv = biasp[c];
#pragma unroll
            for (int t = 0; t < 2; ++t) {
                const long mb = mo2 + wm * 32 + t * 16 + (lane >> 4) * 4;
#pragma unroll
                for (int r4 = 0; r4 < 4; ++r4)
                    out2[(mb + r4) * 320 + c] = f2bs(acc2[t][u][r4] + bv);
            }
        }
    }
}

// ---------------- classifier ----------------
__global__ __launch_bounds__(64) void cls_kernel(
    const short* __restrict__ roots, const float* __restrict__ W_cls,
    const float* __restrict__ b_cls, float* __restrict__ out)
{
    const int b    = blockIdx.x;
    const int lane = threadIdx.x;
    const short* row = roots + (long)b * 640;

    float a0 = 0.f, a1 = 0.f, a2 = 0.f;
#pragma unroll
    for (int i = 0; i < 10; ++i) {
        const int k = lane + 64 * i;
        if (k < 600) {
            const int col = (k < 300) ? k : k + 20;
            const float f = 1.f / (1.f + __expf(-bs2f(row[col])));
            a0 += f * W_cls[k];
            a1 += f * W_cls[600 + k];
            a2 += f * W_cls[1200 + k];
        }
    }
#pragma unroll
    for (int off = 32; off > 0; off >>= 1) {
        a0 += __shfl_down(a0, off);
        a1 += __shfl_down(a1, off);
        a2 += __shfl_down(a2, off);
    }
    if (lane == 0) {
        const float l0 = a0 + b_cls[0];
        const float l1 = a1 + b_cls[1];
        const float l2 = a2 + b_cls[2];
        const float m  = fmaxf(l0, fmaxf(l1, l2));
        const float s  = __expf(l0 - m) + __expf(l1 - m) + __expf(l2 - m);
        const float ls = m + __logf(s);
        out[b * 3 + 0] = l0 - ls;
        out[b * 3 + 1] = l1 - ls;
        out[b * 3 + 2] = l2 - ls;
    }
}

extern "C" void kernel_launch(void* const* d_in, const int* in_sizes, int n_in,
                              void* d_out, int out_size, void* d_ws, size_t ws_size,
                              hipStream_t stream)
{
    const int*   wid    = (const int*)d_in[0];     // (512,2,256) int32
    const float* emb    = (const float*)d_in[1];   // (50000,300) f32
    const float* W_leaf = (const float*)d_in[2];   // (300,300)
    const float* W_h    = (const float*)d_in[3];   // (300,600)
    const float* b_h    = (const float*)d_in[4];   // (300,)
    const float* W_cls  = (const float*)d_in[5];   // (3,600)
    const float* b_cls  = (const float*)d_in[6];   // (3,)
    float* outp = (float*)d_out;                   // (512,3) f32

    (void)in_sizes; (void)n_in; (void)out_size; (void)ws_size;

    // ws layout (peak 158,557,440 B):
    //   bufA   @ 0           : 131072*320*2 =  83,886,080  (tree ping)
    //   bufB   @  83,886,080 :  65536*320*2 =  41,943,040  (tree pong)
    //   emb_bf @  83,886,080 : 50176*320*2  =  32,112,640  (ALIASES bufB: dead
    //            after Hv GEMM; bufB first written at L2, which runs later)
    //   Hv     @ 125,829,120 : 50176*320*2  =  32,112,640
    //   Bleaf  @ 157,941,760 : 320*320*2    =     204,800
    //   Bh     @ 158,146,560 : 320*640*2    =     409,600
    //   biasp  @ 158,556,160 : 320*4        =       1,280
    char* ws = (char*)d_ws;
    short* bufA   = (short*)(ws);
    short* bufB   = (short*)(ws + 83886080);
    short* emb_bf = (short*)(ws + 83886080);
    short* Hv     = (short*)(ws + 125829120);
    short* Bleaf  = (short*)(ws + 157941760);
    short* Bh     = (short*)(ws + 158146560);
    float* biasp  = (float*)(ws + 158556160);

    conv_emb<<<(50176 * 80) / 256, 256, 0, stream>>>(emb, emb_bf);
    conv_w  <<<(307520 + 255) / 256, 256, 0, stream>>>(
        W_h, W_leaf, b_h, Bh, Bleaf, biasp);

    // Vocab-level leaf transform: Hv = emb_bf @ Bleaf^T, M=50176.
    mfma_gemm<320, 0, false><<<50176 / 128, 256, 0, stream>>>(
        emb_bf, nullptr, nullptr, Bleaf, biasp, Hv);

    // L1: node m = W_h @ concat(Hv[wid[2m]], Hv[wid[2m+1]]) + b_h -> bufA.
    mfma_gemm<640, 2, true><<<131072 / 128, 256, 0, stream>>>(
        nullptr, wid, Hv, Bh, biasp, bufA);

    // L2 standalone (512 blocks keep 2 blocks/CU): bufA -> bufB (65536 rows).
    mfma_gemm<640, 0, true><<<65536 / 128, 256, 0, stream>>>(
        bufA, nullptr, nullptr, Bh, biasp, bufB);

    // L3+L4 fused: reads L2 (bufB), L3 stays in LDS, writes L4 -> bufA.
    mfma_pair<<<32768 / 128, 256, 0, stream>>>(bufB, Bh, biasp, bufA);
    // L5+L6 fused: reads L4 (bufA), writes L6 -> bufB.
    mfma_pair<<<8192 / 128, 256, 0, stream>>>(bufA, Bh, biasp, bufB);
    // L7+L8 fused: reads L6 (bufB), writes roots (1024 rows) -> bufA.
    mfma_pair<<<2048 / 128, 256, 0, stream>>>(bufB, Bh, biasp, bufA);

    // roots: bufA 1024 rows x 320 -> 512 x 640 view
    cls_kernel<<<512, 64, 0, stream>>>(bufA, W_cls, b_cls, outp);
}

// Round 10
// 354.629 us; speedup vs baseline: 1.2880x; 1.0178x over previous
//
#include <hip/hip_runtime.h>
#include <hip/hip_bf16.h>

typedef __hip_bfloat16 bf16;
typedef __attribute__((ext_vector_type(8))) short short8;   // 8 bf16 = 4 VGPRs
typedef __attribute__((ext_vector_type(4))) float float4v;  // MFMA C/D
typedef __attribute__((ext_vector_type(4))) short short4v;

__device__ __forceinline__ short f2bs(float x) {
    bf16 b = __float2bfloat16(x);
    return *reinterpret_cast<short*>(&b);
}
__device__ __forceinline__ float bs2f(short s) {
    bf16 b = *reinterpret_cast<bf16*>(&s);
    return __bfloat162float(b);
}

#define GLL16(g, l) __builtin_amdgcn_global_load_lds(                      \
    (const __attribute__((address_space(1))) void*)(g),                    \
    (__attribute__((address_space(3))) void*)(l), 16, 0, 0)

// ---------------- preprocessing: f32 -> padded bf16 layouts ----------------

// emb (50000,300) f32 -> emb_bf (50176,320) bf16. float4 loads.
__global__ __launch_bounds__(256) void conv_emb(
    const float* __restrict__ src, short* __restrict__ dst)
{
    const int idx = blockIdx.x * 256 + threadIdx.x;      // 50176*80
    if (idx >= 50176 * 80) return;
    const int row = idx / 80;
    const int k4  = (idx - row * 80) * 4;
    short4v v = (short4v)0;
    if (row < 50000 && k4 < 300) {
        const float4v f = *reinterpret_cast<const float4v*>(
            src + (long)row * 300 + k4);
#pragma unroll
        for (int j = 0; j < 4; ++j) v[j] = f2bs(f[j]);
    }
    *(short4v*)&dst[(long)row * 320 + k4] = v;
}

// Fused weight prep: W_h -> Bh (320x640), W_leaf -> Bleaf (320x320),
// b_h -> biasp (320).
__global__ __launch_bounds__(256) void conv_w(
    const float* __restrict__ W_h, const float* __restrict__ W_leaf,
    const float* __restrict__ b_h, short* __restrict__ Bh,
    short* __restrict__ Bleaf, float* __restrict__ biasp)
{
    const int idx = blockIdx.x * 256 + threadIdx.x;
    if (idx < 204800) {                                   // Bh 320x640
        const int row = idx / 640, k = idx - row * 640;
        float v = 0.f;
        if (row < 300) {
            if (k < 300)                  v = W_h[row * 600 + k];
            else if (k >= 320 && k < 620) v = W_h[row * 600 + k - 20];
        }
        Bh[idx] = f2bs(v);
    } else if (idx < 307200) {                            // Bleaf 320x320
        const int i = idx - 204800;
        const int row = i / 320, k = i - row * 320;
        Bleaf[i] = (row < 300 && k < 300) ? f2bs(W_leaf[row * 300 + k])
                                          : (short)0;
    } else if (idx < 307520) {                            // biasp 320
        const int i = idx - 307200;
        biasp[i] = (i < 300) ? b_h[i] : 0.f;
    }
}

// ---------------- MFMA GEMM (BK=32, 2-buf, 1-deep counted vmcnt) ----------
// Used for Hv (throughput, KE=320) and L1 (gather, KE=640, 2 blocks/CU TLP).
template <int KE, int GMODE, bool BIAS>
__global__ __launch_bounds__(256, 2) void mfma_gemm(
    const short* __restrict__ Xsrc, const int* __restrict__ wid,
    const short* __restrict__ emb, const short* __restrict__ Wp,
    const float* __restrict__ biasp, short* __restrict__ out)
{
    static_assert(GMODE != 2 || KE == 640, "pair-gather requires KE=640");
    __shared__ __align__(16) short As[2][128 * 32];   // 2 x 8 KB
    __shared__ __align__(16) short Bs[2][320 * 32];   // 2 x 20 KB

    const int tid  = threadIdx.x;
    const int lane = tid & 63;
    const int w    = tid >> 6;
    const int wm   = w >> 1, wn = w & 1;
    const long m0  = (long)blockIdx.x * 128;

    const int s_q   = lane & 3;
    const int r_off = lane >> 2;

    const char* gL[2];
    const char* gR[2];
#pragma unroll
    for (int j = 0; j < 2; ++j) {
        const int r = (w * 2 + j) * 16 + r_off;            // 0..127
        const int q = s_q ^ ((r >> 1) & 3);
        if (GMODE == 2) {
            const long node = m0 + r;
            gL[j] = (const char*)emb + (long)wid[2 * node]     * 640 + q * 16;
            gR[j] = (const char*)emb + (long)wid[2 * node + 1] * 640 + q * 16;
        } else {
            gL[j] = (const char*)Xsrc + (m0 + r) * (long)(KE * 2) + q * 16;
            gR[j] = gL[j];
        }
    }
    const char* gB[5];
#pragma unroll
    for (int j = 0; j < 5; ++j) {
        const int r = (w * 5 + j) * 16 + r_off;            // 0..319
        const int q = s_q ^ ((r >> 1) & 3);
        gB[j] = (const char*)Wp + r * (long)(KE * 2) + q * 16;
    }

    int oA[4];
#pragma unroll
    for (int t = 0; t < 4; ++t) {
        const int row = wm * 64 + t * 16 + (lane & 15);
        const int s   = (lane >> 4) ^ ((row >> 1) & 3);
        oA[t] = row * 32 + s * 8;
    }
    int oB[10];
#pragma unroll
    for (int u = 0; u < 10; ++u) {
        const int n = wn * 160 + u * 16 + (lane & 15);
        const int s = (lane >> 4) ^ ((n >> 1) & 3);
        oB[u] = n * 32 + s * 8;
    }

    auto stage = [&](int buf, int kc) {
        char* baseA = (char*)&As[buf][0];
        char* baseB = (char*)&Bs[buf][0];
        if (GMODE == 2) {
            const bool lft = (kc < 10);
            const int off = (lft ? kc : kc - 10) * 64;
            GLL16((lft ? gL[0] : gR[0]) + off, baseA + (w * 2 + 0) * 1024);
            GLL16((lft ? gL[1] : gR[1]) + off, baseA + (w * 2 + 1) * 1024);
        } else {
            const int off = kc * 64;
            GLL16(gL[0] + off, baseA + (w * 2 + 0) * 1024);
            GLL16(gL[1] + off, baseA + (w * 2 + 1) * 1024);
        }
        const int offb = kc * 64;
#pragma unroll
        for (int j = 0; j < 5; ++j)
            GLL16(gB[j] + offb, baseB + (w * 5 + j) * 1024);
    };

    float4v acc[4][10];
#pragma unroll
    for (int t = 0; t < 4; ++t)
#pragma unroll
        for (int u = 0; u < 10; ++u) acc[t][u] = (float4v)0.f;

    const int NCH = KE / 32;
    stage(0, 0);
    for (int kc = 0; kc < NCH; ++kc) {
        const int cur = kc & 1;
        if (kc + 1 < NCH) {
            stage(cur ^ 1, kc + 1);
            asm volatile("s_waitcnt vmcnt(7)" ::: "memory");
        } else {
            asm volatile("s_waitcnt vmcnt(0)" ::: "memory");
        }
        __builtin_amdgcn_s_barrier();
        __builtin_amdgcn_sched_barrier(0);

        const short* bA = &As[cur][0];
        const short* bB = &Bs[cur][0];
        short8 a[4], b[10];
#pragma unroll
        for (int t = 0; t < 4; ++t) a[t] = *(const short8*)(bA + oA[t]);
#pragma unroll
        for (int u = 0; u < 10; ++u) b[u] = *(const short8*)(bB + oB[u]);
#pragma unroll
        for (int u = 0; u < 10; ++u)
#pragma unroll
            for (int t = 0; t < 4; ++t)
                acc[t][u] = __builtin_amdgcn_mfma_f32_16x16x32_bf16(
                    a[t], b[u], acc[t][u], 0, 0, 0);
        __builtin_amdgcn_s_barrier();
    }

#pragma unroll
    for (int u = 0; u < 10; ++u) {
        const int c = wn * 160 + u * 16 + (lane & 15);
        const float bv = BIAS ? biasp[c] : 0.f;
#pragma unroll
        for (int t = 0; t < 4; ++t) {
            const long mb = m0 + wm * 64 + t * 16 + (lane >> 4) * 4;
#pragma unroll
            for (int r4 = 0; r4 < 4; ++r4)
                out[(mb + r4) * 320 + c] = f2bs(acc[t][u][r4] + bv);
        }
    }
}

// ---------------- BK=128 latency-optimized level GEMM (tree tail) ----------
// out(M,320) = X(M,640) @ Bh(320,640)^T + bias. M=128 rows/block.
// 512 thr = 8 waves, 2x4 grid (wave tile 64 M x 80 N = 4x5 frags).
// Single-buffered LDS: A 4 planes x 8KB = 32KB, B 4 planes x 20KB = 80KB.
// K=640 in 5 chunks of 128 (4 x 32-k planes per chunk): the serial K-chain
// is 5 steps instead of 20 -> 4x fewer latency exposures per level. Plane
// order p=0..3 within chunk preserves the BK=32 accumulation order exactly
// (bit-identical results). Per-plane layout/swizzle identical to mfma_gemm.
__global__ __launch_bounds__(512, 1) void mfma_bk(
    const short* __restrict__ Xsrc, const short* __restrict__ Wp,
    const float* __restrict__ biasp, short* __restrict__ out)
{
    __shared__ __align__(16) short As[4 * 128 * 32];   // 32 KB
    __shared__ __align__(16) short Bs[4 * 320 * 32];   // 80 KB

    const int tid  = threadIdx.x;
    const int lane = tid & 63;
    const int w    = tid >> 6;            // 0..7
    const int wm   = w >> 2;              // 0..1 -> M-tile 64
    const int wn   = w & 3;               // 0..3 -> N-tile 80
    const long m0  = (long)blockIdx.x * 128;

    const int s_q   = lane & 3;
    const int r_off = lane >> 2;          // 0..15

    // A staging: wave w stages rows w*16..w*16+15, one GLL16/thread/plane.
    const int rA = w * 16 + r_off;                      // 0..127
    const int qA = s_q ^ ((rA >> 1) & 3);
    const char* gA = (const char*)Xsrc + (m0 + rA) * (long)(640 * 2) + qA * 16;

    // B staging: 10 (plane,group) slots per wave: gid = w*10+i,
    // plane = gid/20 (wave-uniform), group = gid%20 (16 rows each).
    const char* gB[10];
    int pB[10], loB[10];
#pragma unroll
    for (int i = 0; i < 10; ++i) {
        const int gid = w * 10 + i;
        const int p   = gid / 20;
        const int grp = gid - p * 20;
        const int r   = grp * 16 + r_off;               // 0..319
        const int q   = s_q ^ ((r >> 1) & 3);
        gB[i]  = (const char*)Wp + r * (long)(640 * 2) + q * 16;
        pB[i]  = p;
        loB[i] = p * 20480 + grp * 1024;                // bytes into Bs
    }

    // fragment LDS offsets (shorts, plane-base added at use)
    int oA[4];
#pragma unroll
    for (int t = 0; t < 4; ++t) {
        const int row = wm * 64 + t * 16 + (lane & 15);
        const int s   = (lane >> 4) ^ ((row >> 1) & 3);
        oA[t] = row * 32 + s * 8;
    }
    int oB[5];
#pragma unroll
    for (int u = 0; u < 5; ++u) {
        const int n = wn * 80 + u * 16 + (lane & 15);
        const int s = (lane >> 4) ^ ((n >> 1) & 3);
        oB[u] = n * 32 + s * 8;
    }

    float4v acc[4][5];
#pragma unroll
    for (int t = 0; t < 4; ++t)
#pragma unroll
        for (int u = 0; u < 5; ++u) acc[t][u] = (float4v)0.f;

    for (int kc = 0; kc < 5; ++kc) {
        // stage planes 4kc..4kc+3 (A: 4 GLL/thread, B: 10 GLL/thread)
#pragma unroll
        for (int p = 0; p < 4; ++p) {
            const int pk = kc * 4 + p;
            GLL16(gA + (long)pk * 64, (char*)As + p * 8192 + w * 1024);
        }
#pragma unroll
        for (int i = 0; i < 10; ++i)
            GLL16(gB[i] + (long)(kc * 4 + pB[i]) * 64, (char*)Bs + loB[i]);

        asm volatile("s_waitcnt vmcnt(0)" ::: "memory");
        __builtin_amdgcn_s_barrier();       // chunk landed for all waves
        __builtin_amdgcn_sched_barrier(0);

#pragma unroll
        for (int p = 0; p < 4; ++p) {
            const short* bA = As + p * 4096;
            const short* bB = Bs + p * 10240;
            short8 a[4], b[5];
#pragma unroll
            for (int t = 0; t < 4; ++t) a[t] = *(const short8*)(bA + oA[t]);
#pragma unroll
            for (int u = 0; u < 5; ++u) b[u] = *(const short8*)(bB + oB[u]);
#pragma unroll
            for (int u = 0; u < 5; ++u)
#pragma unroll
                for (int t = 0; t < 4; ++t)
                    acc[t][u] = __builtin_amdgcn_mfma_f32_16x16x32_bf16(
                        a[t], b[u], acc[t][u], 0, 0, 0);
        }
        __builtin_amdgcn_s_barrier();       // reads done; next stage may write
    }

    // epilogue: C/D layout col=lane&15, row=(lane>>4)*4+reg
#pragma unroll
    for (int u = 0; u < 5; ++u) {
        const int c = wn * 80 + u * 16 + (lane & 15);
        const float bv = biasp[c];
#pragma unroll
        for (int t = 0; t < 4; ++t) {
            const long mb = m0 + wm * 64 + t * 16 + (lane >> 4) * 4;
#pragma unroll
            for (int r4 = 0; r4 < 4; ++r4)
                out[(mb + r4) * 320 + c] = f2bs(acc[t][u][r4] + bv);
        }
    }
}

// ---------------- classifier ----------------
__global__ __launch_bounds__(64) void cls_kernel(
    const short* __restrict__ roots, const float* __restrict__ W_cls,
    const float* __restrict__ b_cls, float* __restrict__ out)
{
    const int b    = blockIdx.x;
    const int lane = threadIdx.x;
    const short* row = roots + (long)b * 640;

    float a0 = 0.f, a1 = 0.f, a2 = 0.f;
#pragma unroll
    for (int i = 0; i < 10; ++i) {
        const int k = lane + 64 * i;
        if (k < 600) {
            const int col = (k < 300) ? k : k + 20;
            const float f = 1.f / (1.f + __expf(-bs2f(row[col])));
            a0 += f * W_cls[k];
            a1 += f * W_cls[600 + k];
            a2 += f * W_cls[1200 + k];
        }
    }
#pragma unroll
    for (int off = 32; off > 0; off >>= 1) {
        a0 += __shfl_down(a0, off);
        a1 += __shfl_down(a1, off);
        a2 += __shfl_down(a2, off);
    }
    if (lane == 0) {
        const float l0 = a0 + b_cls[0];
        const float l1 = a1 + b_cls[1];
        const float l2 = a2 + b_cls[2];
        const float m  = fmaxf(l0, fmaxf(l1, l2));
        const float s  = __expf(l0 - m) + __expf(l1 - m) + __expf(l2 - m);
        const float ls = m + __logf(s);
        out[b * 3 + 0] = l0 - ls;
        out[b * 3 + 1] = l1 - ls;
        out[b * 3 + 2] = l2 - ls;
    }
}

extern "C" void kernel_launch(void* const* d_in, const int* in_sizes, int n_in,
                              void* d_out, int out_size, void* d_ws, size_t ws_size,
                              hipStream_t stream)
{
    const int*   wid    = (const int*)d_in[0];     // (512,2,256) int32
    const float* emb    = (const float*)d_in[1];   // (50000,300) f32
    const float* W_leaf = (const float*)d_in[2];   // (300,300)
    const float* W_h    = (const float*)d_in[3];   // (300,600)
    const float* b_h    = (const float*)d_in[4];   // (300,)
    const float* W_cls  = (const float*)d_in[5];   // (3,600)
    const float* b_cls  = (const float*)d_in[6];   // (3,)
    float* outp = (float*)d_out;                   // (512,3) f32

    (void)in_sizes; (void)n_in; (void)out_size; (void)ws_size;

    // ws layout (peak 158,557,440 B):
    //   bufA   @ 0           : 131072*320*2 =  83,886,080  (tree ping)
    //   bufB   @  83,886,080 :  65536*320*2 =  41,943,040  (tree pong)
    //   emb_bf @  83,886,080 : 50176*320*2  =  32,112,640  (ALIASES bufB: dead
    //            after Hv GEMM; bufB first written by L2, which runs later)
    //   Hv     @ 125,829,120 : 50176*320*2  =  32,112,640
    //   Bleaf  @ 157,941,760 : 320*320*2    =     204,800
    //   Bh     @ 158,146,560 : 320*640*2    =     409,600
    //   biasp  @ 158,556,160 : 320*4        =       1,280
    char* ws = (char*)d_ws;
    short* bufA   = (short*)(ws);
    short* bufB   = (short*)(ws + 83886080);
    short* emb_bf = (short*)(ws + 83886080);
    short* Hv     = (short*)(ws + 125829120);
    short* Bleaf  = (short*)(ws + 157941760);
    short* Bh     = (short*)(ws + 158146560);
    float* biasp  = (float*)(ws + 158556160);

    conv_emb<<<(50176 * 80) / 256, 256, 0, stream>>>(emb, emb_bf);
    conv_w  <<<(307520 + 255) / 256, 256, 0, stream>>>(
        W_h, W_leaf, b_h, Bh, Bleaf, biasp);

    // Vocab-level leaf transform: Hv = emb_bf @ Bleaf^T, M=50176.
    mfma_gemm<320, 0, false><<<50176 / 128, 256, 0, stream>>>(
        emb_bf, nullptr, nullptr, Bleaf, biasp, Hv);

    // L1: node m = W_h @ concat(Hv[wid[2m]], Hv[wid[2m+1]]) + b_h -> bufA.
    mfma_gemm<640, 2, true><<<131072 / 128, 256, 0, stream>>>(
        nullptr, wid, Hv, Bh, biasp, bufA);

    // L2..L8: BK=128 latency-optimized levels, ping-pong bufA <-> bufB.
    short* cur = bufA;
    short* nxt = bufB;
    int nodes = 65536;
    for (int l = 0; l < 7; ++l) {
        mfma_bk<<<nodes / 128, 512, 0, stream>>>(cur, Bh, biasp, nxt);
        short* t = cur; cur = nxt; nxt = t;
        nodes >>= 1;
    }
    // roots: cur holds 1024 rows x 320 -> 512 x 640 view

    cls_kernel<<<512, 64, 0, stream>>>(cur, W_cls, b_cls, outp);
}